// Round 1
// baseline (357.099 us; speedup 1.0000x reference)
//
#include <hip/hip_runtime.h>
#include <math.h>

#define B_  2
#define L_  2048
#define D_  512
#define NH_ 8
#define HD_ 64
#define HB_ 16   // NH_*B_

__device__ __forceinline__ float ex2(float x) {
#if __has_builtin(__builtin_amdgcn_exp2f)
    return __builtin_amdgcn_exp2f(x);
#else
    return exp2f(x);
#endif
}
__device__ __forceinline__ float rcp_(float x) {
#if __has_builtin(__builtin_amdgcn_rcpf)
    return __builtin_amdgcn_rcpf(x);
#else
    return 1.0f / x;
#endif
}

// exp(tanh(x)):  z=e^{2x}; tanh=1-2/(z+1); e^tanh via exp2
__device__ __forceinline__ float fast_e(float x) {
    float z  = ex2(x * 2.885390082f);        // e^{2x} = 2^{2x*log2(e)}
    float th = 1.0f - 2.0f * rcp_(z + 1.0f);
    return ex2(th * 1.4426950408889634f);
}

// ---------------------------------------------------------------------------
// K1: fold w_score into Wq/Wk:  wqwT[h][i] = sum_d Wq[i][h*64+d]*w1[d]
// grid 4 x 256.  blocks 0,1 -> Wq (row halves), 2,3 -> Wk
// ---------------------------------------------------------------------------
__global__ void k_prep(const float* __restrict__ Wq, const float* __restrict__ bq,
                       const float* __restrict__ Wk, const float* __restrict__ bk,
                       const float* __restrict__ wsc,
                       float* __restrict__ wqwT, float* __restrict__ wkwT,
                       float* __restrict__ bqw, float* __restrict__ bkw) {
    __shared__ float w[HD_];
    int which = blockIdx.x >> 1;
    int half  = blockIdx.x & 1;
    const float* W  = which ? Wk : Wq;
    const float* bb = which ? bk : bq;
    float* WT = which ? wkwT : wqwT;
    float* bo = which ? bkw  : bqw;
    if (threadIdx.x < HD_) w[threadIdx.x] = wsc[which * HD_ + threadIdx.x];
    __syncthreads();
    int r = half * 256 + threadIdx.x;
    for (int h = 0; h < NH_; ++h) {
        float s = 0.f;
        #pragma unroll 8
        for (int d = 0; d < HD_; ++d) s += W[r * D_ + h * HD_ + d] * w[d];
        WT[h * D_ + r] = s;
    }
    if (half == 0 && threadIdx.x < NH_) {
        int h = threadIdx.x;
        float s = 0.f;
        for (int d = 0; d < HD_; ++d) s += bb[h * HD_ + d] * w[d];
        bo[h] = s;
    }
}

// ---------------------------------------------------------------------------
// K2: qw = q @ wqwT + bqw ; kw = k @ wkwT + bkw.  One wave per row.
// grid 2048 x 256 (4 waves/block; rows 0..4095 = q, 4096..8191 = k)
// qw layout: [h][b*2048+q]  == [hb][q]
// ---------------------------------------------------------------------------
__global__ void k_qwkw(const float* __restrict__ q, const float* __restrict__ k,
                       const float* __restrict__ wqwT, const float* __restrict__ wkwT,
                       const float* __restrict__ bqw, const float* __restrict__ bkw,
                       float* __restrict__ qw, float* __restrict__ kw) {
    int wid  = blockIdx.x * 4 + (threadIdx.x >> 6);
    int lane = threadIdx.x & 63;
    int sel  = wid >= 4096;
    int row  = wid & 4095;
    const float* src = sel ? k : q;
    const float* WT  = sel ? wkwT : wqwT;
    const float* bo  = sel ? bkw : bqw;
    float* dst = sel ? kw : qw;
    float4 va = *(const float4*)(src + (size_t)row * D_ + lane * 4);
    float4 vb = *(const float4*)(src + (size_t)row * D_ + 256 + lane * 4);
    float res[NH_];
    #pragma unroll
    for (int h = 0; h < NH_; ++h) {
        float4 wa = *(const float4*)(WT + h * D_ + lane * 4);
        float4 wb = *(const float4*)(WT + h * D_ + 256 + lane * 4);
        float s = va.x*wa.x + va.y*wa.y + va.z*wa.z + va.w*wa.w
                + vb.x*wb.x + vb.y*wb.y + vb.z*wb.z + vb.w*wb.w;
        #pragma unroll
        for (int off = 32; off; off >>= 1) s += __shfl_xor(s, off);
        res[h] = s + bo[h];
    }
    if (lane == 0) {
        #pragma unroll
        for (int h = 0; h < NH_; ++h) dst[h * 4096 + row] = res[h];
    }
}

// ---------------------------------------------------------------------------
// K3/K6: fp32 GEMM  C = A(4096x512) @ Bm(512x512) + bias
// MODE 0: scatter to vx[(h*2+b)*2048+k][d] ; MODE 1: plain row-major
// grid (32, 8), 256 threads.  BM=128 BN=64 KC=16, 8x4 microtile.
// ---------------------------------------------------------------------------
template<int MODE>
__global__ __launch_bounds__(256) void k_gemm(const float* __restrict__ A,
                                              const float* __restrict__ Bm,
                                              const float* __restrict__ bias,
                                              float* __restrict__ C) {
    __shared__ float As[16][136];
    __shared__ float Bs[16][68];
    int m0 = blockIdx.x * 128;
    int n0 = blockIdx.y * 64;
    int tid = threadIdx.x;
    int tx = tid & 15, ty = tid >> 4;
    float acc[8][4];
    #pragma unroll
    for (int i = 0; i < 8; ++i)
        #pragma unroll
        for (int j = 0; j < 4; ++j) acc[i][j] = 0.f;

    int am = tid & 127, ak = (tid >> 7) * 8;
    int bk = tid >> 4,  bn = (tid & 15) * 4;

    for (int k0 = 0; k0 < 512; k0 += 16) {
        float4 a0 = *(const float4*)(A + (size_t)(m0 + am) * 512 + k0 + ak);
        float4 a1 = *(const float4*)(A + (size_t)(m0 + am) * 512 + k0 + ak + 4);
        float4 b0 = *(const float4*)(Bm + (size_t)(k0 + bk) * 512 + n0 + bn);
        __syncthreads();
        As[ak + 0][am] = a0.x; As[ak + 1][am] = a0.y;
        As[ak + 2][am] = a0.z; As[ak + 3][am] = a0.w;
        As[ak + 4][am] = a1.x; As[ak + 5][am] = a1.y;
        As[ak + 6][am] = a1.z; As[ak + 7][am] = a1.w;
        *(float4*)&Bs[bk][bn] = b0;
        __syncthreads();
        #pragma unroll
        for (int kk = 0; kk < 16; ++kk) {
            float4 aA = *(const float4*)&As[kk][ty * 8];
            float4 aB = *(const float4*)&As[kk][ty * 8 + 4];
            float4 bb = *(const float4*)&Bs[kk][tx * 4];
            float a[8] = {aA.x, aA.y, aA.z, aA.w, aB.x, aB.y, aB.z, aB.w};
            float b[4] = {bb.x, bb.y, bb.z, bb.w};
            #pragma unroll
            for (int i = 0; i < 8; ++i)
                #pragma unroll
                for (int j = 0; j < 4; ++j) acc[i][j] += a[i] * b[j];
        }
    }
    const float4 bsv = *(const float4*)(bias + n0 + tx * 4);
    #pragma unroll
    for (int i = 0; i < 8; ++i) {
        int m = m0 + ty * 8 + i;
        float4 o;
        o.x = acc[i][0] + bsv.x; o.y = acc[i][1] + bsv.y;
        o.z = acc[i][2] + bsv.z; o.w = acc[i][3] + bsv.w;
        if (MODE == 0) {
            int c = n0 + tx * 4;
            int h = c >> 6, b = m >> 11, kk2 = m & 2047;
            *(float4*)(C + (((size_t)(h * 2 + b) * 2048 + kk2) * 64 + (c & 63))) = o;
        } else {
            *(float4*)(C + (size_t)m * 512 + n0 + tx * 4) = o;
        }
    }
}

// ---------------------------------------------------------------------------
// K4: main fused kernel. One block = (hb, 64 q-rows). 512 threads = 8 waves.
// wave -> (kq = w&3: k-segment of 512, dh = w>>2: d-half of 32).
// lane -> q-row. Single pass: sum(e) and acc += e*vx; normalize at end.
// vx chunks staged in LDS; inner reads are wave-uniform broadcasts.
// ---------------------------------------------------------------------------
__global__ __launch_bounds__(512) void k_main(const float* __restrict__ qw,
                                              const float* __restrict__ kw,
                                              const float* __restrict__ vx,
                                              float* __restrict__ att,
                                              float* __restrict__ rsum_o) {
    int hb = blockIdx.y;
    int q0 = blockIdx.x * 64;
    int tid = threadIdx.x;
    int w    = tid >> 6;
    int lane = tid & 63;
    int kq = w & 3;
    int dh = w >> 2;
    int q  = q0 + lane;

    __shared__ float kws[2048];
    __shared__ float vxs[4][8][68];
    __shared__ float red[64][68];

    *(float4*)&kws[tid * 4] = *(const float4*)(kw + hb * 2048 + tid * 4);
    float qwv = qw[hb * 2048 + q];
    const float* vbase = vx + (size_t)hb * 2048 * 64;

    float acc[32];
    #pragma unroll
    for (int d = 0; d < 32; ++d) acc[d] = 0.f;
    float sum = 0.f;

    int f   = tid;
    int seg = f >> 7;
    int kk0 = (f >> 4) & 7;
    int dp  = (f & 15) * 4;

    for (int c = 0; c < 64; ++c) {
        float4 vld = *(const float4*)(vbase + ((size_t)(seg * 512 + c * 8 + kk0) * 64 + dp));
        __syncthreads();                      // prior-iter reads done
        *(float4*)&vxs[seg][kk0][dp] = vld;
        __syncthreads();
        int kbase = kq * 512 + c * 8;
        #pragma unroll
        for (int kk = 0; kk < 8; ++kk) {
            float e = fast_e(qwv + kws[kbase + kk]);
            if (dh == 0) sum += e;
            const float* vp = &vxs[kq][kk][dh * 32];
            #pragma unroll
            for (int d4 = 0; d4 < 8; ++d4) {
                float4 v = *(const float4*)(vp + d4 * 4);
                acc[d4*4+0] += e * v.x; acc[d4*4+1] += e * v.y;
                acc[d4*4+2] += e * v.z; acc[d4*4+3] += e * v.w;
            }
        }
    }

    // cross-wave reduce: waves with same kq add their partials (disjoint cols)
    for (int r = 0; r < 4; ++r) {
        if (kq == r) {
            if (r == 0) {
                #pragma unroll
                for (int d = 0; d < 32; ++d) red[lane][dh * 32 + d] = acc[d];
                if (dh == 0) red[lane][64] = sum;
            } else {
                #pragma unroll
                for (int d = 0; d < 32; ++d) red[lane][dh * 32 + d] += acc[d];
                if (dh == 0) red[lane][64] += sum;
            }
        }
        __syncthreads();
    }

    // writeout: 512 threads -> 64 rows x 8 d-octets
    {
        int row = tid >> 3;
        int i8  = (tid & 7) * 8;
        float rs = 1.0f / red[row][64];
        float4 o0, o1;
        o0.x = red[row][i8+0]*rs; o0.y = red[row][i8+1]*rs;
        o0.z = red[row][i8+2]*rs; o0.w = red[row][i8+3]*rs;
        o1.x = red[row][i8+4]*rs; o1.y = red[row][i8+5]*rs;
        o1.z = red[row][i8+6]*rs; o1.w = red[row][i8+7]*rs;
        int b = hb & 1, h = hb >> 1;
        int gq = q0 + row;
        float* dst = att + ((size_t)(b * 2048 + gq) * 512 + h * 64 + i8);
        *(float4*)dst = o0;
        *(float4*)(dst + 4) = o1;
        if ((tid & 7) == 0) rsum_o[hb * 2048 + gq] = rs;
    }
}

// ---------------------------------------------------------------------------
// K5: score writer — fully coalesced 256MB write.
// grid (256, 16), 256 threads: 8 q-rows/block, 32 threads/row.
// ---------------------------------------------------------------------------
__global__ void k_score(const float* __restrict__ qw, const float* __restrict__ kw,
                        const float* __restrict__ rsum, float* __restrict__ score) {
    int hb = blockIdx.y;
    int tid = threadIdx.x;
    __shared__ float kws[2048];
    *(float4*)&kws[tid * 8]     = *(const float4*)(kw + hb * 2048 + tid * 8);
    *(float4*)&kws[tid * 8 + 4] = *(const float4*)(kw + hb * 2048 + tid * 8 + 4);
    __syncthreads();
    int rl  = tid >> 5;
    int t32 = tid & 31;
    int q = blockIdx.x * 8 + rl;
    float qwv = qw[hb * 2048 + q];
    float rs  = rsum[hb * 2048 + q];
    float* out = score + ((size_t)(hb * 2048 + q)) * 2048;
    #pragma unroll
    for (int i = 0; i < 16; ++i) {
        int k = i * 128 + t32 * 4;
        float4 o;
        o.x = fast_e(qwv + kws[k + 0]) * rs;
        o.y = fast_e(qwv + kws[k + 1]) * rs;
        o.z = fast_e(qwv + kws[k + 2]) * rs;
        o.w = fast_e(qwv + kws[k + 3]) * rs;
        *(float4*)(out + k) = o;
    }
}

// ---------------------------------------------------------------------------
extern "C" void kernel_launch(void* const* d_in, const int* in_sizes, int n_in,
                              void* d_out, int out_size, void* d_ws, size_t ws_size,
                              hipStream_t stream) {
    (void)in_sizes; (void)n_in; (void)out_size; (void)ws_size;
    const float* q   = (const float*)d_in[0];
    const float* k   = (const float*)d_in[1];
    const float* v   = (const float*)d_in[2];
    const float* Wq  = (const float*)d_in[3];
    const float* bq  = (const float*)d_in[4];
    const float* Wk  = (const float*)d_in[5];
    const float* bk  = (const float*)d_in[6];
    const float* Wv  = (const float*)d_in[7];
    const float* bv  = (const float*)d_in[8];
    const float* wsc = (const float*)d_in[9];
    const float* Wd  = (const float*)d_in[10];
    const float* bd  = (const float*)d_in[11];

    float* out   = (float*)d_out;                       // (2,2048,512)
    float* score = out + (size_t)B_ * L_ * D_;          // (16,2048,2048)

    float* ws    = (float*)d_ws;
    float* wqwT  = ws;                // 4096
    float* wkwT  = ws + 4096;         // 4096
    float* bqw   = ws + 8192;         // 8
    float* bkw   = ws + 8200;         // 8
    float* qw    = ws + 8704;         // 32768
    float* kw    = ws + 41472;        // 32768
    float* rsum  = ws + 74240;        // 32768
    float* vx    = ws + 107008;       // 2097152  [hb][k][64]
    float* att   = ws + 2204160;      // 2097152  [b][q][512]

    k_prep<<<dim3(4), dim3(256), 0, stream>>>(Wq, bq, Wk, bk, wsc, wqwT, wkwT, bqw, bkw);
    k_qwkw<<<dim3(2048), dim3(256), 0, stream>>>(q, k, wqwT, wkwT, bqw, bkw, qw, kw);
    k_gemm<0><<<dim3(32, 8), dim3(256), 0, stream>>>(v, Wv, bv, vx);
    k_main<<<dim3(32, 16), dim3(512), 0, stream>>>(qw, kw, vx, att, rsum);
    k_score<<<dim3(256, 16), dim3(256), 0, stream>>>(qw, kw, rsum, score);
    k_gemm<1><<<dim3(32, 8), dim3(256), 0, stream>>>(att, Wd, bd, out);
}

// Round 3
// 225.784 us; speedup vs baseline: 1.5816x; 1.5816x over previous
//
#include <hip/hip_runtime.h>
#include <math.h>

#define B_  2
#define L_  2048
#define D_  512
#define NH_ 8
#define HD_ 64

typedef __attribute__((ext_vector_type(8))) short short8;
typedef __attribute__((ext_vector_type(4))) float f32x4;

__device__ __forceinline__ float ex2(float x) {
#if __has_builtin(__builtin_amdgcn_exp2f)
    return __builtin_amdgcn_exp2f(x);
#else
    return exp2f(x);
#endif
}
__device__ __forceinline__ float rcp_(float x) {
#if __has_builtin(__builtin_amdgcn_rcpf)
    return __builtin_amdgcn_rcpf(x);
#else
    return 1.0f / x;
#endif
}

// exp(tanh(x)):  z=e^{2x}; tanh=1-2/(z+1); e^tanh via exp2
__device__ __forceinline__ float fast_e(float x) {
    float z  = ex2(x * 2.885390082f);        // e^{2x} = 2^{2x*log2(e)}
    float th = 1.0f - 2.0f * rcp_(z + 1.0f);
    return ex2(th * 1.4426950408889634f);
}

__device__ __forceinline__ unsigned int f2bf(float x) {
    unsigned int u = __float_as_uint(x);
    u += 0x7fffu + ((u >> 16) & 1u);         // RNE
    return u >> 16;
}
__device__ __forceinline__ unsigned int pk2(float lo, float hi) {
    return f2bf(lo) | (f2bf(hi) << 16);
}

// ---------------------------------------------------------------------------
// K1: fold w_score into Wq/Wk:  wqwT[h][i] = sum_d Wq[i][h*64+d]*w1[d]
// ---------------------------------------------------------------------------
__global__ void k_prep(const float* __restrict__ Wq, const float* __restrict__ bq,
                       const float* __restrict__ Wk, const float* __restrict__ bk,
                       const float* __restrict__ wsc,
                       float* __restrict__ wqwT, float* __restrict__ wkwT,
                       float* __restrict__ bqw, float* __restrict__ bkw) {
    __shared__ float w[HD_];
    int which = blockIdx.x >> 1;
    int half  = blockIdx.x & 1;
    const float* W  = which ? Wk : Wq;
    const float* bb = which ? bk : bq;
    float* WT = which ? wkwT : wqwT;
    float* bo = which ? bkw  : bqw;
    if (threadIdx.x < HD_) w[threadIdx.x] = wsc[which * HD_ + threadIdx.x];
    __syncthreads();
    int r = half * 256 + threadIdx.x;
    for (int h = 0; h < NH_; ++h) {
        float s = 0.f;
        #pragma unroll 8
        for (int d = 0; d < HD_; ++d) s += W[r * D_ + h * HD_ + d] * w[d];
        WT[h * D_ + r] = s;
    }
    if (half == 0 && threadIdx.x < NH_) {
        int h = threadIdx.x;
        float s = 0.f;
        for (int d = 0; d < HD_; ++d) s += bb[h * HD_ + d] * w[d];
        bo[h] = s;
    }
}

// ---------------------------------------------------------------------------
// K2: qw = q @ wqwT + bqw ; kw = k @ wkwT + bkw.  One wave per row.
// qw layout: [h][b*2048+q]  == [hb][q]
// ---------------------------------------------------------------------------
__global__ void k_qwkw(const float* __restrict__ q, const float* __restrict__ k,
                       const float* __restrict__ wqwT, const float* __restrict__ wkwT,
                       const float* __restrict__ bqw, const float* __restrict__ bkw,
                       float* __restrict__ qw, float* __restrict__ kw) {
    int wid  = blockIdx.x * 4 + (threadIdx.x >> 6);
    int lane = threadIdx.x & 63;
    int sel  = wid >= 4096;
    int row  = wid & 4095;
    const float* src = sel ? k : q;
    const float* WT  = sel ? wkwT : wqwT;
    const float* bo  = sel ? bkw : bqw;
    float* dst = sel ? kw : qw;
    float4 va = *(const float4*)(src + (size_t)row * D_ + lane * 4);
    float4 vb = *(const float4*)(src + (size_t)row * D_ + 256 + lane * 4);
    float res[NH_];
    #pragma unroll
    for (int h = 0; h < NH_; ++h) {
        float4 wa = *(const float4*)(WT + h * D_ + lane * 4);
        float4 wb = *(const float4*)(WT + h * D_ + 256 + lane * 4);
        float s = va.x*wa.x + va.y*wa.y + va.z*wa.z + va.w*wa.w
                + vb.x*wb.x + vb.y*wb.y + vb.z*wb.z + vb.w*wb.w;
        #pragma unroll
        for (int off = 32; off; off >>= 1) s += __shfl_xor(s, off);
        res[h] = s + bo[h];
    }
    if (lane == 0) {
        #pragma unroll
        for (int h = 0; h < NH_; ++h) dst[h * 4096 + row] = res[h];
    }
}

// ---------------------------------------------------------------------------
// K3/K6: fp32 GEMM  C = A(4096x512) @ Bm(512x512) + bias
// MODE 0: store bf16 in MFMA B-fragment order: [hb][kblk][dt][lane][8]
// MODE 1: plain row-major fp32
// ---------------------------------------------------------------------------
template<int MODE>
__global__ __launch_bounds__(256) void k_gemm(const float* __restrict__ A,
                                              const float* __restrict__ Bm,
                                              const float* __restrict__ bias,
                                              float* __restrict__ C) {
    __shared__ float As[16][136];
    __shared__ float Bs[16][68];
    int m0 = blockIdx.x * 128;
    int n0 = blockIdx.y * 64;
    int tid = threadIdx.x;
    int tx = tid & 15, ty = tid >> 4;
    float acc[8][4];
    #pragma unroll
    for (int i = 0; i < 8; ++i)
        #pragma unroll
        for (int j = 0; j < 4; ++j) acc[i][j] = 0.f;

    int am = tid & 127, ak = (tid >> 7) * 8;
    int bk = tid >> 4,  bn = (tid & 15) * 4;

    for (int k0 = 0; k0 < 512; k0 += 16) {
        float4 a0 = *(const float4*)(A + (size_t)(m0 + am) * 512 + k0 + ak);
        float4 a1 = *(const float4*)(A + (size_t)(m0 + am) * 512 + k0 + ak + 4);
        float4 b0 = *(const float4*)(Bm + (size_t)(k0 + bk) * 512 + n0 + bn);
        __syncthreads();
        As[ak + 0][am] = a0.x; As[ak + 1][am] = a0.y;
        As[ak + 2][am] = a0.z; As[ak + 3][am] = a0.w;
        As[ak + 4][am] = a1.x; As[ak + 5][am] = a1.y;
        As[ak + 6][am] = a1.z; As[ak + 7][am] = a1.w;
        *(float4*)&Bs[bk][bn] = b0;
        __syncthreads();
        #pragma unroll
        for (int kk = 0; kk < 16; ++kk) {
            float4 aA = *(const float4*)&As[kk][ty * 8];
            float4 aB = *(const float4*)&As[kk][ty * 8 + 4];
            float4 bb = *(const float4*)&Bs[kk][tx * 4];
            float a[8] = {aA.x, aA.y, aA.z, aA.w, aB.x, aB.y, aB.z, aB.w};
            float b[4] = {bb.x, bb.y, bb.z, bb.w};
            #pragma unroll
            for (int i = 0; i < 8; ++i)
                #pragma unroll
                for (int j = 0; j < 4; ++j) acc[i][j] += a[i] * b[j];
        }
    }
    const float4 bsv = *(const float4*)(bias + n0 + tx * 4);
    #pragma unroll
    for (int i = 0; i < 8; ++i) {
        int m = m0 + ty * 8 + i;
        float o0 = acc[i][0] + bsv.x, o1 = acc[i][1] + bsv.y;
        float o2 = acc[i][2] + bsv.z, o3 = acc[i][3] + bsv.w;
        if (MODE == 0) {
            // m = b*2048 + k ; n = h*64 + d  -> bf16 fragment layout
            unsigned short* Cb = (unsigned short*)C;
            int bb2 = m >> 11, kk2 = m & 2047;
            int n = n0 + tx * 4;
            int h = n >> 6;
            int hb = h * 2 + bb2;
            int kblk = kk2 >> 5, k32 = kk2 & 31;
            int dt = (n >> 4) & 3;
            int ncol = n & 15;
            int lane_l = ncol + 16 * ((k32 >> 2) & 3);
            int ie = (k32 & 3) + 4 * (k32 >> 4);
            size_t base = (((size_t)(hb * 64 + kblk) * 4 + dt) * 64 + lane_l) * 8 + ie;
            Cb[base + 0]  = (unsigned short)f2bf(o0);
            Cb[base + 8]  = (unsigned short)f2bf(o1);
            Cb[base + 16] = (unsigned short)f2bf(o2);
            Cb[base + 24] = (unsigned short)f2bf(o3);
        } else {
            float4 o = {o0, o1, o2, o3};
            *(float4*)(C + (size_t)m * 512 + n0 + tx * 4) = o;
        }
    }
}

// ---------------------------------------------------------------------------
// K4: main fused kernel, MFMA PV, B-fragments straight from global (L2-hot).
// Block = 256 thr = 4 waves; wave wq owns 16 q-rows, all 2048 k, d=64.
// A-fragment of E synthesized in registers (fast_e + plain-C bf16 pack).
// ---------------------------------------------------------------------------
__global__ __launch_bounds__(256) void k_main(const float* __restrict__ qw,
                                              const float* __restrict__ kw,
                                              const short8* __restrict__ vgs,
                                              float* __restrict__ att,
                                              float* __restrict__ rsum_o) {
    int hb  = blockIdx.y;
    int q0  = blockIdx.x * 64;
    int tid = threadIdx.x;
    int wq  = tid >> 6;
    int lane = tid & 63;
    int l15 = lane & 15, lg = lane >> 4;

    __shared__ float kws[2048];                 // 8 KB only
    *(float4*)&kws[tid * 8]     = *(const float4*)(kw + hb * 2048 + tid * 8);
    *(float4*)&kws[tid * 8 + 4] = *(const float4*)(kw + hb * 2048 + tid * 8 + 4);
    __syncthreads();

    float qwv = qw[hb * 2048 + q0 + wq * 16 + l15];
    // vgs fragment layout: [hb][kblk(64)][dt(4)][lane(64)] short8
    const short8* bp = vgs + (size_t)hb * 16384 + lane;

    f32x4 acc0 = {0,0,0,0}, acc1 = {0,0,0,0}, acc2 = {0,0,0,0}, acc3 = {0,0,0,0};
    float sum = 0.f;

    for (int kblk = 0; kblk < 64; ++kblk) {
        int kidx = kblk * 32 + lg * 4;
        float4 kw0 = *(const float4*)&kws[kidx];
        float4 kw1 = *(const float4*)&kws[kidx + 16];
        float e0 = fast_e(qwv + kw0.x), e1 = fast_e(qwv + kw0.y);
        float e2 = fast_e(qwv + kw0.z), e3 = fast_e(qwv + kw0.w);
        float e4 = fast_e(qwv + kw1.x), e5 = fast_e(qwv + kw1.y);
        float e6 = fast_e(qwv + kw1.z), e7 = fast_e(qwv + kw1.w);
        sum += ((e0 + e1) + (e2 + e3)) + ((e4 + e5) + (e6 + e7));
        union { unsigned int u[4]; short8 s; } af;
        af.u[0] = pk2(e0, e1);
        af.u[1] = pk2(e2, e3);
        af.u[2] = pk2(e4, e5);
        af.u[3] = pk2(e6, e7);
        const short8* b = bp + kblk * 256;
        short8 b0 = b[0];
        short8 b1 = b[64];
        short8 b2 = b[128];
        short8 b3 = b[192];
        acc0 = __builtin_amdgcn_mfma_f32_16x16x32_bf16(af.s, b0, acc0, 0, 0, 0);
        acc1 = __builtin_amdgcn_mfma_f32_16x16x32_bf16(af.s, b1, acc1, 0, 0, 0);
        acc2 = __builtin_amdgcn_mfma_f32_16x16x32_bf16(af.s, b2, acc2, 0, 0, 0);
        acc3 = __builtin_amdgcn_mfma_f32_16x16x32_bf16(af.s, b3, acc3, 0, 0, 0);
    }

    // row sums: lane covers (row=l15, k-slice lg); combine the 4 lg groups
    sum += __shfl_xor(sum, 16);
    sum += __shfl_xor(sum, 32);
    float rs = 1.0f / sum;
    if (lane < 16) rsum_o[hb * 2048 + q0 + wq * 16 + lane] = rs;

    int b_ = hb & 1, h = hb >> 1;
    float r0s = __shfl(rs, lg * 4 + 0);
    float r1s = __shfl(rs, lg * 4 + 1);
    float r2s = __shfl(rs, lg * 4 + 2);
    float r3s = __shfl(rs, lg * 4 + 3);
    // C/D layout (m89): col = lane&15 (=d within 16-block), row = lg*4 + reg
    float* ab = att + ((size_t)(b_ * 2048 + q0 + wq * 16 + lg * 4)) * 512 + h * 64 + l15;
    #define ST_(dt, accv) \
        ab[0 * 512 + dt * 16] = accv[0] * r0s; \
        ab[1 * 512 + dt * 16] = accv[1] * r1s; \
        ab[2 * 512 + dt * 16] = accv[2] * r2s; \
        ab[3 * 512 + dt * 16] = accv[3] * r3s;
    ST_(0, acc0) ST_(1, acc1) ST_(2, acc2) ST_(3, acc3)
    #undef ST_
}

// ---------------------------------------------------------------------------
// K5: score writer — fully coalesced 256MB write (fp32 path, uses rsum).
// ---------------------------------------------------------------------------
__global__ void k_score(const float* __restrict__ qw, const float* __restrict__ kw,
                        const float* __restrict__ rsum, float* __restrict__ score) {
    int hb = blockIdx.y;
    int tid = threadIdx.x;
    __shared__ float kws[2048];
    *(float4*)&kws[tid * 8]     = *(const float4*)(kw + hb * 2048 + tid * 8);
    *(float4*)&kws[tid * 8 + 4] = *(const float4*)(kw + hb * 2048 + tid * 8 + 4);
    __syncthreads();
    int rl  = tid >> 5;
    int t32 = tid & 31;
    int q = blockIdx.x * 8 + rl;
    float qwv = qw[hb * 2048 + q];
    float rs  = rsum[hb * 2048 + q];
    float* out = score + ((size_t)(hb * 2048 + q)) * 2048;
    #pragma unroll
    for (int i = 0; i < 16; ++i) {
        int k = i * 128 + t32 * 4;
        float4 o;
        o.x = fast_e(qwv + kws[k + 0]) * rs;
        o.y = fast_e(qwv + kws[k + 1]) * rs;
        o.z = fast_e(qwv + kws[k + 2]) * rs;
        o.w = fast_e(qwv + kws[k + 3]) * rs;
        *(float4*)(out + k) = o;
    }
}

// ---------------------------------------------------------------------------
extern "C" void kernel_launch(void* const* d_in, const int* in_sizes, int n_in,
                              void* d_out, int out_size, void* d_ws, size_t ws_size,
                              hipStream_t stream) {
    (void)in_sizes; (void)n_in; (void)out_size; (void)ws_size;
    const float* q   = (const float*)d_in[0];
    const float* k   = (const float*)d_in[1];
    const float* v   = (const float*)d_in[2];
    const float* Wq  = (const float*)d_in[3];
    const float* bq  = (const float*)d_in[4];
    const float* Wk  = (const float*)d_in[5];
    const float* bk  = (const float*)d_in[6];
    const float* Wv  = (const float*)d_in[7];
    const float* bv  = (const float*)d_in[8];
    const float* wsc = (const float*)d_in[9];
    const float* Wd  = (const float*)d_in[10];
    const float* bd  = (const float*)d_in[11];

    float* out   = (float*)d_out;                       // (2,2048,512)
    float* score = out + (size_t)B_ * L_ * D_;          // (16,2048,2048)

    float* ws    = (float*)d_ws;
    float* wqwT  = ws;                 // 4096
    float* wkwT  = ws + 4096;          // 4096
    float* bqw   = ws + 8192;          // 8 (padded)
    float* bkw   = ws + 8256;          // 8 (padded)
    float* qw    = ws + 8704;          // 32768
    float* kw    = ws + 41472;         // 32768
    float* rsum  = ws + 74240;         // 32768
    float* vxg   = ws + 107008;        // 2,097,152 bf16 = 1,048,576 f32 slots
    float* att   = ws + 1155584;       // 2,097,152 f32

    k_prep<<<dim3(4), dim3(256), 0, stream>>>(Wq, bq, Wk, bk, wsc, wqwT, wkwT, bqw, bkw);
    k_qwkw<<<dim3(2048), dim3(256), 0, stream>>>(q, k, wqwT, wkwT, bqw, bkw, qw, kw);
    k_gemm<0><<<dim3(32, 8), dim3(256), 0, stream>>>(v, Wv, bv, vxg);
    k_main<<<dim3(32, 16), dim3(256), 0, stream>>>(qw, kw, (const short8*)vxg, att, rsum);
    k_score<<<dim3(256, 16), dim3(256), 0, stream>>>(qw, kw, rsum, score);
    k_gemm<1><<<dim3(32, 8), dim3(256), 0, stream>>>(att, Wd, bd, out);
}

// Round 4
// 174.704 us; speedup vs baseline: 2.0440x; 1.2924x over previous
//
#include <hip/hip_runtime.h>
#include <math.h>

#define B_  2
#define L_  2048
#define D_  512
#define NH_ 8
#define HD_ 64

typedef __attribute__((ext_vector_type(8))) short short8;
typedef __attribute__((ext_vector_type(4))) float f32x4;

__device__ __forceinline__ float ex2(float x) {
#if __has_builtin(__builtin_amdgcn_exp2f)
    return __builtin_amdgcn_exp2f(x);
#else
    return exp2f(x);
#endif
}
__device__ __forceinline__ float rcp_(float x) {
#if __has_builtin(__builtin_amdgcn_rcpf)
    return __builtin_amdgcn_rcpf(x);
#else
    return 1.0f / x;
#endif
}

// exp(tanh(x)):  z=e^{2x}; tanh=1-2/(z+1); e^tanh via exp2
__device__ __forceinline__ float fast_e(float x) {
    float z  = ex2(x * 2.885390082f);        // e^{2x} = 2^{2x*log2(e)}
    float th = 1.0f - 2.0f * rcp_(z + 1.0f);
    return ex2(th * 1.4426950408889634f);
}

__device__ __forceinline__ unsigned int f2bf(float x) {
    unsigned int u = __float_as_uint(x);
    u += 0x7fffu + ((u >> 16) & 1u);         // RNE
    return u >> 16;
}
__device__ __forceinline__ unsigned int pk2(float lo, float hi) {
    return f2bf(lo) | (f2bf(hi) << 16);
}

// ---------------------------------------------------------------------------
// K1: fold w_score into Wq/Wk:  wqwT[h][i] = sum_d Wq[i][h*64+d]*w1[d]
// ---------------------------------------------------------------------------
__global__ void k_prep(const float* __restrict__ Wq, const float* __restrict__ bq,
                       const float* __restrict__ Wk, const float* __restrict__ bk,
                       const float* __restrict__ wsc,
                       float* __restrict__ wqwT, float* __restrict__ wkwT,
                       float* __restrict__ bqw, float* __restrict__ bkw) {
    __shared__ float w[HD_];
    int which = blockIdx.x >> 1;
    int half  = blockIdx.x & 1;
    const float* W  = which ? Wk : Wq;
    const float* bb = which ? bk : bq;
    float* WT = which ? wkwT : wqwT;
    float* bo = which ? bkw  : bqw;
    if (threadIdx.x < HD_) w[threadIdx.x] = wsc[which * HD_ + threadIdx.x];
    __syncthreads();
    int r = half * 256 + threadIdx.x;
    for (int h = 0; h < NH_; ++h) {
        float s = 0.f;
        #pragma unroll 8
        for (int d = 0; d < HD_; ++d) s += W[r * D_ + h * HD_ + d] * w[d];
        WT[h * D_ + r] = s;
    }
    if (half == 0 && threadIdx.x < NH_) {
        int h = threadIdx.x;
        float s = 0.f;
        for (int d = 0; d < HD_; ++d) s += bb[h * HD_ + d] * w[d];
        bo[h] = s;
    }
}

// ---------------------------------------------------------------------------
// K1b: build B-fragment planes.
//  y=0: WvF  = bf16(Wv) in fragment layout [nf(32)][kb(16)][lane(64)][ie(8)]
//  y=1: WdFh/WdFl = hi/lo split of Wd, same layout
// frag semantics: n = nf*16 + (lane&15), k = kb*32 + (lane>>4)*4 + (ie&3) + 16*(ie>>2)
// ---------------------------------------------------------------------------
__global__ void k_wconv(const float* __restrict__ Wv, const float* __restrict__ Wd,
                        unsigned short* __restrict__ WvF,
                        unsigned short* __restrict__ WdFh,
                        unsigned short* __restrict__ WdFl) {
    int id = blockIdx.x * 256 + threadIdx.x;   // 0..32767
    int lane = id & 63;
    int kb = (id >> 6) & 15;
    int nf = id >> 10;                          // 0..31
    int l15 = lane & 15, lg = lane >> 4;
    int n = nf * 16 + l15;
    int k0 = kb * 32 + lg * 4;
    size_t base = ((size_t)(nf * 16 + kb) * 64 + lane) * 8;
    if (blockIdx.y == 0) {
        #pragma unroll
        for (int j = 0; j < 8; ++j) {
            int k = k0 + (j & 3) + 16 * (j >> 2);
            WvF[base + j] = (unsigned short)f2bf(Wv[(size_t)k * 512 + n]);
        }
    } else {
        #pragma unroll
        for (int j = 0; j < 8; ++j) {
            int k = k0 + (j & 3) + 16 * (j >> 2);
            float x = Wd[(size_t)k * 512 + n];
            unsigned int h = f2bf(x);
            float hf = __uint_as_float(h << 16);
            WdFh[base + j] = (unsigned short)h;
            WdFl[base + j] = (unsigned short)f2bf(x - hf);
        }
    }
}

// ---------------------------------------------------------------------------
// K2: qw = q @ wqwT + bqw ; kw = k @ wkwT + bkw.  One wave per row.
// qw layout: [h][b*2048+q]  == [hb][q]
// ---------------------------------------------------------------------------
__global__ void k_qwkw(const float* __restrict__ q, const float* __restrict__ k,
                       const float* __restrict__ wqwT, const float* __restrict__ wkwT,
                       const float* __restrict__ bqw, const float* __restrict__ bkw,
                       float* __restrict__ qw, float* __restrict__ kw) {
    int wid  = blockIdx.x * 4 + (threadIdx.x >> 6);
    int lane = threadIdx.x & 63;
    int sel  = wid >= 4096;
    int row  = wid & 4095;
    const float* src = sel ? k : q;
    const float* WT  = sel ? wkwT : wqwT;
    const float* bo  = sel ? bkw : bqw;
    float* dst = sel ? kw : qw;
    float4 va = *(const float4*)(src + (size_t)row * D_ + lane * 4);
    float4 vb = *(const float4*)(src + (size_t)row * D_ + 256 + lane * 4);
    float res[NH_];
    #pragma unroll
    for (int h = 0; h < NH_; ++h) {
        float4 wa = *(const float4*)(WT + h * D_ + lane * 4);
        float4 wb = *(const float4*)(WT + h * D_ + 256 + lane * 4);
        float s = va.x*wa.x + va.y*wa.y + va.z*wa.z + va.w*wa.w
                + vb.x*wb.x + vb.y*wb.y + vb.z*wb.z + vb.w*wb.w;
        #pragma unroll
        for (int off = 32; off; off >>= 1) s += __shfl_xor(s, off);
        res[h] = s + bo[h];
    }
    if (lane == 0) {
        #pragma unroll
        for (int h = 0; h < NH_; ++h) dst[h * 4096 + row] = res[h];
    }
}

// ---------------------------------------------------------------------------
// K3: GEMM0 = (v @ Wv + bv) -> bf16 vxg fragment layout. Single-bf16 MFMA.
// Block 256thr/4 waves; block tile 128m x 64n; wave = 32m x 64n; K=512.
// A-frags gathered from global fp32 v; B-frags from WvF (L2). No LDS.
// ---------------------------------------------------------------------------
__global__ __launch_bounds__(256) void k_mmA(const float* __restrict__ A,
                                             const short8* __restrict__ BF,
                                             const float* __restrict__ bias,
                                             unsigned short* __restrict__ vxg) {
    int m0 = blockIdx.x * 128;
    int n0q = blockIdx.y * 4;      // base n-frag index
    int tid = threadIdx.x;
    int w = tid >> 6, lane = tid & 63;
    int l15 = lane & 15, lg = lane >> 4;
    f32x4 acc[2][4];
    #pragma unroll
    for (int i = 0; i < 2; ++i)
        #pragma unroll
        for (int j = 0; j < 4; ++j) acc[i][j] = (f32x4){0.f, 0.f, 0.f, 0.f};

    const float* a0 = A + (size_t)(m0 + w * 32 + l15) * 512 + lg * 4;
    const float* a1 = a0 + (size_t)16 * 512;

    for (int kb = 0; kb < 16; ++kb) {
        union { unsigned int u[4]; short8 s; } af0, af1;
        float4 lo0 = *(const float4*)(a0 + kb * 32);
        float4 hi0 = *(const float4*)(a0 + kb * 32 + 16);
        float4 lo1 = *(const float4*)(a1 + kb * 32);
        float4 hi1 = *(const float4*)(a1 + kb * 32 + 16);
        af0.u[0] = pk2(lo0.x, lo0.y); af0.u[1] = pk2(lo0.z, lo0.w);
        af0.u[2] = pk2(hi0.x, hi0.y); af0.u[3] = pk2(hi0.z, hi0.w);
        af1.u[0] = pk2(lo1.x, lo1.y); af1.u[1] = pk2(lo1.z, lo1.w);
        af1.u[2] = pk2(hi1.x, hi1.y); af1.u[3] = pk2(hi1.z, hi1.w);
        #pragma unroll
        for (int nf = 0; nf < 4; ++nf) {
            short8 bb = BF[((size_t)(n0q + nf) * 16 + kb) * 64 + lane];
            acc[0][nf] = __builtin_amdgcn_mfma_f32_16x16x32_bf16(af0.s, bb, acc[0][nf], 0, 0, 0);
            acc[1][nf] = __builtin_amdgcn_mfma_f32_16x16x32_bf16(af1.s, bb, acc[1][nf], 0, 0, 0);
        }
    }
    // epilogue: scatter bf16 into vxg fragment layout (formula verified r3)
    #pragma unroll
    for (int nf = 0; nf < 4; ++nf) {
        int n = (n0q + nf) * 16 + l15;
        float bvv = bias[n];
        int h = n >> 6, dt = (n >> 4) & 3, ncol = n & 15;
        #pragma unroll
        for (int mf = 0; mf < 2; ++mf) {
            #pragma unroll
            for (int r = 0; r < 4; ++r) {
                int m = m0 + w * 32 + mf * 16 + lg * 4 + r;
                int b = m >> 11, kk = m & 2047;
                int kblk = kk >> 5, k32 = kk & 31;
                int lane_v = ncol + 16 * ((k32 >> 2) & 3);
                int ie = (k32 & 3) + 4 * (k32 >> 4);
                size_t ad = ((((size_t)(h * 2 + b) * 64 + kblk) * 4 + dt) * 64 + lane_v) * 8 + ie;
                vxg[ad] = (unsigned short)f2bf(acc[mf][nf][r] + bvv);
            }
        }
    }
}

// ---------------------------------------------------------------------------
// K6: GEMM1 = att @ Wd + bd -> out (fp32).  Split-bf16 MFMA (3 passes):
//   out ~= Ah*Bh + Al*Bh + Ah*Bl   (A split in-register, B pre-split planes)
// Same tiling as k_mmA. No LDS.
// ---------------------------------------------------------------------------
__global__ __launch_bounds__(256) void k_mmB(const float* __restrict__ A,
                                             const short8* __restrict__ BFh,
                                             const short8* __restrict__ BFl,
                                             const float* __restrict__ bias,
                                             float* __restrict__ C) {
    int m0 = blockIdx.x * 128;
    int n0q = blockIdx.y * 4;
    int tid = threadIdx.x;
    int w = tid >> 6, lane = tid & 63;
    int l15 = lane & 15, lg = lane >> 4;
    f32x4 acc[2][4];
    #pragma unroll
    for (int i = 0; i < 2; ++i)
        #pragma unroll
        for (int j = 0; j < 4; ++j) acc[i][j] = (f32x4){0.f, 0.f, 0.f, 0.f};

    const float* a0 = A + (size_t)(m0 + w * 32 + l15) * 512 + lg * 4;

    for (int kb = 0; kb < 16; ++kb) {
        union { unsigned int u[4]; short8 s; } ah[2], al[2];
        #pragma unroll
        for (int mf = 0; mf < 2; ++mf) {
            const float* ap = a0 + (size_t)mf * 16 * 512 + kb * 32;
            float4 lo = *(const float4*)ap;
            float4 hi = *(const float4*)(ap + 16);
            float xs[8] = {lo.x, lo.y, lo.z, lo.w, hi.x, hi.y, hi.z, hi.w};
            unsigned int hu[8]; float lf[8];
            #pragma unroll
            for (int j = 0; j < 8; ++j) {
                hu[j] = f2bf(xs[j]);
                lf[j] = xs[j] - __uint_as_float(hu[j] << 16);
            }
            #pragma unroll
            for (int j = 0; j < 4; ++j) {
                ah[mf].u[j] = hu[2 * j] | (hu[2 * j + 1] << 16);
                al[mf].u[j] = pk2(lf[2 * j], lf[2 * j + 1]);
            }
        }
        #pragma unroll
        for (int nf = 0; nf < 4; ++nf) {
            size_t bi = ((size_t)(n0q + nf) * 16 + kb) * 64 + lane;
            short8 bh = BFh[bi];
            short8 bl = BFl[bi];
            #pragma unroll
            for (int mf = 0; mf < 2; ++mf) {
                acc[mf][nf] = __builtin_amdgcn_mfma_f32_16x16x32_bf16(ah[mf].s, bh, acc[mf][nf], 0, 0, 0);
                acc[mf][nf] = __builtin_amdgcn_mfma_f32_16x16x32_bf16(al[mf].s, bh, acc[mf][nf], 0, 0, 0);
                acc[mf][nf] = __builtin_amdgcn_mfma_f32_16x16x32_bf16(ah[mf].s, bl, acc[mf][nf], 0, 0, 0);
            }
        }
    }
    #pragma unroll
    for (int nf = 0; nf < 4; ++nf) {
        int n = (n0q + nf) * 16 + l15;
        float bdv = bias[n];
        #pragma unroll
        for (int mf = 0; mf < 2; ++mf) {
            #pragma unroll
            for (int r = 0; r < 4; ++r) {
                int m = m0 + w * 32 + mf * 16 + lg * 4 + r;
                C[(size_t)m * 512 + n] = acc[mf][nf][r] + bdv;
            }
        }
    }
}

// ---------------------------------------------------------------------------
// K4: main fused kernel, MFMA PV, B-fragments straight from global (L2-hot).
// ---------------------------------------------------------------------------
__global__ __launch_bounds__(256) void k_main(const float* __restrict__ qw,
                                              const float* __restrict__ kw,
                                              const short8* __restrict__ vgs,
                                              float* __restrict__ att,
                                              float* __restrict__ rsum_o) {
    int hb  = blockIdx.y;
    int q0  = blockIdx.x * 64;
    int tid = threadIdx.x;
    int wq  = tid >> 6;
    int lane = tid & 63;
    int l15 = lane & 15, lg = lane >> 4;

    __shared__ float kws[2048];                 // 8 KB only
    *(float4*)&kws[tid * 8]     = *(const float4*)(kw + hb * 2048 + tid * 8);
    *(float4*)&kws[tid * 8 + 4] = *(const float4*)(kw + hb * 2048 + tid * 8 + 4);
    __syncthreads();

    float qwv = qw[hb * 2048 + q0 + wq * 16 + l15];
    const short8* bp = vgs + (size_t)hb * 16384 + lane;

    f32x4 acc0 = {0,0,0,0}, acc1 = {0,0,0,0}, acc2 = {0,0,0,0}, acc3 = {0,0,0,0};
    float sum = 0.f;

    for (int kblk = 0; kblk < 64; ++kblk) {
        int kidx = kblk * 32 + lg * 4;
        float4 kw0 = *(const float4*)&kws[kidx];
        float4 kw1 = *(const float4*)&kws[kidx + 16];
        float e0 = fast_e(qwv + kw0.x), e1 = fast_e(qwv + kw0.y);
        float e2 = fast_e(qwv + kw0.z), e3 = fast_e(qwv + kw0.w);
        float e4 = fast_e(qwv + kw1.x), e5 = fast_e(qwv + kw1.y);
        float e6 = fast_e(qwv + kw1.z), e7 = fast_e(qwv + kw1.w);
        sum += ((e0 + e1) + (e2 + e3)) + ((e4 + e5) + (e6 + e7));
        union { unsigned int u[4]; short8 s; } af;
        af.u[0] = pk2(e0, e1);
        af.u[1] = pk2(e2, e3);
        af.u[2] = pk2(e4, e5);
        af.u[3] = pk2(e6, e7);
        const short8* b = bp + kblk * 256;
        short8 b0 = b[0];
        short8 b1 = b[64];
        short8 b2 = b[128];
        short8 b3 = b[192];
        acc0 = __builtin_amdgcn_mfma_f32_16x16x32_bf16(af.s, b0, acc0, 0, 0, 0);
        acc1 = __builtin_amdgcn_mfma_f32_16x16x32_bf16(af.s, b1, acc1, 0, 0, 0);
        acc2 = __builtin_amdgcn_mfma_f32_16x16x32_bf16(af.s, b2, acc2, 0, 0, 0);
        acc3 = __builtin_amdgcn_mfma_f32_16x16x32_bf16(af.s, b3, acc3, 0, 0, 0);
    }

    sum += __shfl_xor(sum, 16);
    sum += __shfl_xor(sum, 32);
    float rs = 1.0f / sum;
    if (lane < 16) rsum_o[hb * 2048 + q0 + wq * 16 + lane] = rs;

    int b_ = hb & 1, h = hb >> 1;
    float r0s = __shfl(rs, lg * 4 + 0);
    float r1s = __shfl(rs, lg * 4 + 1);
    float r2s = __shfl(rs, lg * 4 + 2);
    float r3s = __shfl(rs, lg * 4 + 3);
    float* ab = att + ((size_t)(b_ * 2048 + q0 + wq * 16 + lg * 4)) * 512 + h * 64 + l15;
    #define ST_(dt, accv) \
        ab[0 * 512 + dt * 16] = accv[0] * r0s; \
        ab[1 * 512 + dt * 16] = accv[1] * r1s; \
        ab[2 * 512 + dt * 16] = accv[2] * r2s; \
        ab[3 * 512 + dt * 16] = accv[3] * r3s;
    ST_(0, acc0) ST_(1, acc1) ST_(2, acc2) ST_(3, acc3)
    #undef ST_
}

// ---------------------------------------------------------------------------
// K5: score writer — fully coalesced 256MB write (fp32 path, uses rsum).
// ---------------------------------------------------------------------------
__global__ void k_score(const float* __restrict__ qw, const float* __restrict__ kw,
                        const float* __restrict__ rsum, float* __restrict__ score) {
    int hb = blockIdx.y;
    int tid = threadIdx.x;
    __shared__ float kws[2048];
    *(float4*)&kws[tid * 8]     = *(const float4*)(kw + hb * 2048 + tid * 8);
    *(float4*)&kws[tid * 8 + 4] = *(const float4*)(kw + hb * 2048 + tid * 8 + 4);
    __syncthreads();
    int rl  = tid >> 5;
    int t32 = tid & 31;
    int q = blockIdx.x * 8 + rl;
    float qwv = qw[hb * 2048 + q];
    float rs  = rsum[hb * 2048 + q];
    float* out = score + ((size_t)(hb * 2048 + q)) * 2048;
    #pragma unroll
    for (int i = 0; i < 16; ++i) {
        int k = i * 128 + t32 * 4;
        float4 o;
        o.x = fast_e(qwv + kws[k + 0]) * rs;
        o.y = fast_e(qwv + kws[k + 1]) * rs;
        o.z = fast_e(qwv + kws[k + 2]) * rs;
        o.w = fast_e(qwv + kws[k + 3]) * rs;
        *(float4*)(out + k) = o;
    }
}

// ---------------------------------------------------------------------------
extern "C" void kernel_launch(void* const* d_in, const int* in_sizes, int n_in,
                              void* d_out, int out_size, void* d_ws, size_t ws_size,
                              hipStream_t stream) {
    (void)in_sizes; (void)n_in; (void)out_size; (void)ws_size;
    const float* q   = (const float*)d_in[0];
    const float* k   = (const float*)d_in[1];
    const float* v   = (const float*)d_in[2];
    const float* Wq  = (const float*)d_in[3];
    const float* bq  = (const float*)d_in[4];
    const float* Wk  = (const float*)d_in[5];
    const float* bk  = (const float*)d_in[6];
    const float* Wv  = (const float*)d_in[7];
    const float* bv  = (const float*)d_in[8];
    const float* wsc = (const float*)d_in[9];
    const float* Wd  = (const float*)d_in[10];
    const float* bd  = (const float*)d_in[11];

    float* out   = (float*)d_out;                       // (2,2048,512)
    float* score = out + (size_t)B_ * L_ * D_;          // (16,2048,2048)

    float* ws    = (float*)d_ws;
    float* wqwT  = ws;                 // 4096
    float* wkwT  = ws + 4096;          // 4096
    float* bqw   = ws + 8192;          // 8 (padded)
    float* bkw   = ws + 8256;          // 8 (padded)
    float* qw    = ws + 8704;          // 32768
    float* kw    = ws + 41472;         // 32768
    float* rsum  = ws + 74240;         // 32768
    float* vxg   = ws + 107008;        // 2,097,152 bf16 = 1,048,576 f32 slots
    float* att   = ws + 1155584;       // 2,097,152 f32
    float* WvF   = ws + 3252736;       // 262,144 bf16 = 131,072 f32 slots
    float* WdFh  = ws + 3383808;       // 131,072 f32 slots
    float* WdFl  = ws + 3514880;       // 131,072 f32 slots

    k_prep<<<dim3(4), dim3(256), 0, stream>>>(Wq, bq, Wk, bk, wsc, wqwT, wkwT, bqw, bkw);
    k_wconv<<<dim3(128, 2), dim3(256), 0, stream>>>(Wv, Wd,
        (unsigned short*)WvF, (unsigned short*)WdFh, (unsigned short*)WdFl);
    k_qwkw<<<dim3(2048), dim3(256), 0, stream>>>(q, k, wqwT, wkwT, bqw, bkw, qw, kw);
    k_mmA<<<dim3(32, 8), dim3(256), 0, stream>>>(v, (const short8*)WvF, bv,
        (unsigned short*)vxg);
    k_main<<<dim3(32, 16), dim3(256), 0, stream>>>(qw, kw, (const short8*)vxg, att, rsum);
    k_score<<<dim3(256, 16), dim3(256), 0, stream>>>(qw, kw, rsum, score);
    k_mmB<<<dim3(32, 8), dim3(256), 0, stream>>>(att, (const short8*)WdFh,
        (const short8*)WdFl, bd, out);
}

// Round 5
// 164.135 us; speedup vs baseline: 2.1756x; 1.0644x over previous
//
#include <hip/hip_runtime.h>
#include <math.h>

#define B_  2
#define L_  2048
#define D_  512
#define NH_ 8
#define HD_ 64

typedef __attribute__((ext_vector_type(8))) short short8;
typedef __attribute__((ext_vector_type(4))) float f32x4;

__device__ __forceinline__ float ex2(float x) {
#if __has_builtin(__builtin_amdgcn_exp2f)
    return __builtin_amdgcn_exp2f(x);
#else
    return exp2f(x);
#endif
}
__device__ __forceinline__ float rcp_(float x) {
#if __has_builtin(__builtin_amdgcn_rcpf)
    return __builtin_amdgcn_rcpf(x);
#else
    return 1.0f / x;
#endif
}

// exp(tanh(x)):  z=e^{2x}; tanh=1-2/(z+1); e^tanh via exp2
__device__ __forceinline__ float fast_e(float x) {
    float z  = ex2(x * 2.885390082f);        // e^{2x} = 2^{2x*log2(e)}
    float th = 1.0f - 2.0f * rcp_(z + 1.0f);
    return ex2(th * 1.4426950408889634f);
}

__device__ __forceinline__ unsigned int f2bf(float x) {
    unsigned int u = __float_as_uint(x);
    u += 0x7fffu + ((u >> 16) & 1u);         // RNE
    return u >> 16;
}
__device__ __forceinline__ unsigned int pk2(float lo, float hi) {
    return f2bf(lo) | (f2bf(hi) << 16);
}

// ---------------------------------------------------------------------------
// K1: fold w_score into Wq/Wk:  wqwT[h][i] = sum_d Wq[i][h*64+d]*w1[d]
// ---------------------------------------------------------------------------
__global__ void k_prep(const float* __restrict__ Wq, const float* __restrict__ bq,
                       const float* __restrict__ Wk, const float* __restrict__ bk,
                       const float* __restrict__ wsc,
                       float* __restrict__ wqwT, float* __restrict__ wkwT,
                       float* __restrict__ bqw, float* __restrict__ bkw) {
    __shared__ float w[HD_];
    int which = blockIdx.x >> 1;
    int half  = blockIdx.x & 1;
    const float* W  = which ? Wk : Wq;
    const float* bb = which ? bk : bq;
    float* WT = which ? wkwT : wqwT;
    float* bo = which ? bkw  : bqw;
    if (threadIdx.x < HD_) w[threadIdx.x] = wsc[which * HD_ + threadIdx.x];
    __syncthreads();
    int r = half * 256 + threadIdx.x;
    for (int h = 0; h < NH_; ++h) {
        float s = 0.f;
        #pragma unroll 8
        for (int d = 0; d < HD_; ++d) s += W[r * D_ + h * HD_ + d] * w[d];
        WT[h * D_ + r] = s;
    }
    if (half == 0 && threadIdx.x < NH_) {
        int h = threadIdx.x;
        float s = 0.f;
        for (int d = 0; d < HD_; ++d) s += bb[h * HD_ + d] * w[d];
        bo[h] = s;
    }
}

// ---------------------------------------------------------------------------
// K1b: build B-fragment planes.
//  y=0: WvF  = bf16(Wv) in fragment layout [nf(32)][kb(16)][lane(64)][ie(8)]
//  y=1: WdFh/WdFl = hi/lo split of Wd, same layout
// frag semantics: n = nf*16 + (lane&15), k = kb*32 + (lane>>4)*4 + (ie&3) + 16*(ie>>2)
// ---------------------------------------------------------------------------
__global__ void k_wconv(const float* __restrict__ Wv, const float* __restrict__ Wd,
                        unsigned short* __restrict__ WvF,
                        unsigned short* __restrict__ WdFh,
                        unsigned short* __restrict__ WdFl) {
    int id = blockIdx.x * 256 + threadIdx.x;   // 0..32767
    int lane = id & 63;
    int kb = (id >> 6) & 15;
    int nf = id >> 10;                          // 0..31
    int l15 = lane & 15, lg = lane >> 4;
    int n = nf * 16 + l15;
    int k0 = kb * 32 + lg * 4;
    size_t base = ((size_t)(nf * 16 + kb) * 64 + lane) * 8;
    if (blockIdx.y == 0) {
        #pragma unroll
        for (int j = 0; j < 8; ++j) {
            int k = k0 + (j & 3) + 16 * (j >> 2);
            WvF[base + j] = (unsigned short)f2bf(Wv[(size_t)k * 512 + n]);
        }
    } else {
        #pragma unroll
        for (int j = 0; j < 8; ++j) {
            int k = k0 + (j & 3) + 16 * (j >> 2);
            float x = Wd[(size_t)k * 512 + n];
            unsigned int h = f2bf(x);
            float hf = __uint_as_float(h << 16);
            WdFh[base + j] = (unsigned short)h;
            WdFl[base + j] = (unsigned short)f2bf(x - hf);
        }
    }
}

// ---------------------------------------------------------------------------
// K2: qw = q @ wqwT + bqw ; kw = k @ wkwT + bkw.  One wave per row.
// qw layout: [h][b*2048+q]  == [hb][q]
// ---------------------------------------------------------------------------
__global__ void k_qwkw(const float* __restrict__ q, const float* __restrict__ k,
                       const float* __restrict__ wqwT, const float* __restrict__ wkwT,
                       const float* __restrict__ bqw, const float* __restrict__ bkw,
                       float* __restrict__ qw, float* __restrict__ kw) {
    int wid  = blockIdx.x * 4 + (threadIdx.x >> 6);
    int lane = threadIdx.x & 63;
    int sel  = wid >= 4096;
    int row  = wid & 4095;
    const float* src = sel ? k : q;
    const float* WT  = sel ? wkwT : wqwT;
    const float* bo  = sel ? bkw : bqw;
    float* dst = sel ? kw : qw;
    float4 va = *(const float4*)(src + (size_t)row * D_ + lane * 4);
    float4 vb = *(const float4*)(src + (size_t)row * D_ + 256 + lane * 4);
    float res[NH_];
    #pragma unroll
    for (int h = 0; h < NH_; ++h) {
        float4 wa = *(const float4*)(WT + h * D_ + lane * 4);
        float4 wb = *(const float4*)(WT + h * D_ + 256 + lane * 4);
        float s = va.x*wa.x + va.y*wa.y + va.z*wa.z + va.w*wa.w
                + vb.x*wb.x + vb.y*wb.y + vb.z*wb.z + vb.w*wb.w;
        #pragma unroll
        for (int off = 32; off; off >>= 1) s += __shfl_xor(s, off);
        res[h] = s + bo[h];
    }
    if (lane == 0) {
        #pragma unroll
        for (int h = 0; h < NH_; ++h) dst[h * 4096 + row] = res[h];
    }
}

// ---------------------------------------------------------------------------
// K3: GEMM0 = (v @ Wv + bv) -> bf16 vxg fragment layout. Single-bf16 MFMA.
// grid (64,8), 256 thr / 4 waves; block tile 64m x 64n; wave = 16m x 64n.
// Depth-1 prefetch of A (global) and B-frags (L2). No LDS.
// ---------------------------------------------------------------------------
__global__ __launch_bounds__(256) void k_mmA(const float* __restrict__ A,
                                             const short8* __restrict__ BF,
                                             const float* __restrict__ bias,
                                             unsigned short* __restrict__ vxg) {
    int m0 = blockIdx.x * 64;
    int n0q = blockIdx.y * 4;      // base n-frag index
    int tid = threadIdx.x;
    int w = tid >> 6, lane = tid & 63;
    int l15 = lane & 15, lg = lane >> 4;
    f32x4 acc[4];
    #pragma unroll
    for (int j = 0; j < 4; ++j) acc[j] = (f32x4){0.f, 0.f, 0.f, 0.f};

    const float* a0 = A + (size_t)(m0 + w * 16 + l15) * 512 + lg * 4;

    float4 clo = *(const float4*)(a0);
    float4 chi = *(const float4*)(a0 + 16);
    short8 cb[4];
    #pragma unroll
    for (int nf = 0; nf < 4; ++nf) cb[nf] = BF[(size_t)(n0q + nf) * 16 * 64 + lane];

    for (int kb = 0; kb < 16; ++kb) {
        float4 lo = clo, hi = chi;
        short8 b0 = cb[0], b1 = cb[1], b2 = cb[2], b3 = cb[3];
        if (kb < 15) {
            clo = *(const float4*)(a0 + (kb + 1) * 32);
            chi = *(const float4*)(a0 + (kb + 1) * 32 + 16);
            #pragma unroll
            for (int nf = 0; nf < 4; ++nf)
                cb[nf] = BF[((size_t)(n0q + nf) * 16 + kb + 1) * 64 + lane];
        }
        union { unsigned int u[4]; short8 s; } af;
        af.u[0] = pk2(lo.x, lo.y); af.u[1] = pk2(lo.z, lo.w);
        af.u[2] = pk2(hi.x, hi.y); af.u[3] = pk2(hi.z, hi.w);
        acc[0] = __builtin_amdgcn_mfma_f32_16x16x32_bf16(af.s, b0, acc[0], 0, 0, 0);
        acc[1] = __builtin_amdgcn_mfma_f32_16x16x32_bf16(af.s, b1, acc[1], 0, 0, 0);
        acc[2] = __builtin_amdgcn_mfma_f32_16x16x32_bf16(af.s, b2, acc[2], 0, 0, 0);
        acc[3] = __builtin_amdgcn_mfma_f32_16x16x32_bf16(af.s, b3, acc[3], 0, 0, 0);
    }
    // epilogue: scatter bf16 into vxg fragment layout (formula verified r3/r4)
    #pragma unroll
    for (int nf = 0; nf < 4; ++nf) {
        int n = (n0q + nf) * 16 + l15;
        float bvv = bias[n];
        int h = n >> 6, dt = (n >> 4) & 3, ncol = n & 15;
        #pragma unroll
        for (int r = 0; r < 4; ++r) {
            int m = m0 + w * 16 + lg * 4 + r;
            int b = m >> 11, kk = m & 2047;
            int kblk = kk >> 5, k32 = kk & 31;
            int lane_v = ncol + 16 * ((k32 >> 2) & 3);
            int ie = (k32 & 3) + 4 * (k32 >> 4);
            size_t ad = ((((size_t)(h * 2 + b) * 64 + kblk) * 4 + dt) * 64 + lane_v) * 8 + ie;
            vxg[ad] = (unsigned short)f2bf(acc[nf][r] + bvv);
        }
    }
}

// ---------------------------------------------------------------------------
// K6: GEMM1 = att @ Wd + bd -> out (fp32).  Split-bf16 MFMA (3 passes):
//   out ~= Ah*Bh + Al*Bh + Ah*Bl.  grid (64,8); wave = 16m x 64n. No LDS.
// ---------------------------------------------------------------------------
__global__ __launch_bounds__(256) void k_mmB(const float* __restrict__ A,
                                             const short8* __restrict__ BFh,
                                             const short8* __restrict__ BFl,
                                             const float* __restrict__ bias,
                                             float* __restrict__ C) {
    int m0 = blockIdx.x * 64;
    int n0q = blockIdx.y * 4;
    int tid = threadIdx.x;
    int w = tid >> 6, lane = tid & 63;
    int l15 = lane & 15, lg = lane >> 4;
    f32x4 acc[4];
    #pragma unroll
    for (int j = 0; j < 4; ++j) acc[j] = (f32x4){0.f, 0.f, 0.f, 0.f};

    const float* a0 = A + (size_t)(m0 + w * 16 + l15) * 512 + lg * 4;

    float4 clo = *(const float4*)(a0);
    float4 chi = *(const float4*)(a0 + 16);

    for (int kb = 0; kb < 16; ++kb) {
        float4 lo = clo, hi = chi;
        if (kb < 15) {
            clo = *(const float4*)(a0 + (kb + 1) * 32);
            chi = *(const float4*)(a0 + (kb + 1) * 32 + 16);
        }
        union { unsigned int u[4]; short8 s; } ah, al;
        {
            float xs[8] = {lo.x, lo.y, lo.z, lo.w, hi.x, hi.y, hi.z, hi.w};
            unsigned int hu[8]; float lf[8];
            #pragma unroll
            for (int j = 0; j < 8; ++j) {
                hu[j] = f2bf(xs[j]);
                lf[j] = xs[j] - __uint_as_float(hu[j] << 16);
            }
            #pragma unroll
            for (int j = 0; j < 4; ++j) {
                ah.u[j] = hu[2 * j] | (hu[2 * j + 1] << 16);
                al.u[j] = pk2(lf[2 * j], lf[2 * j + 1]);
            }
        }
        #pragma unroll
        for (int nf = 0; nf < 4; ++nf) {
            size_t bi = ((size_t)(n0q + nf) * 16 + kb) * 64 + lane;
            short8 bh = BFh[bi];
            short8 bl = BFl[bi];
            acc[nf] = __builtin_amdgcn_mfma_f32_16x16x32_bf16(ah.s, bh, acc[nf], 0, 0, 0);
            acc[nf] = __builtin_amdgcn_mfma_f32_16x16x32_bf16(al.s, bh, acc[nf], 0, 0, 0);
            acc[nf] = __builtin_amdgcn_mfma_f32_16x16x32_bf16(ah.s, bl, acc[nf], 0, 0, 0);
        }
    }
    #pragma unroll
    for (int nf = 0; nf < 4; ++nf) {
        int n = (n0q + nf) * 16 + l15;
        float bdv = bias[n];
        #pragma unroll
        for (int r = 0; r < 4; ++r) {
            int m = m0 + w * 16 + lg * 4 + r;
            C[(size_t)m * 512 + n] = acc[nf][r] + bdv;
        }
    }
}

// ---------------------------------------------------------------------------
// K4: main fused kernel, MFMA PV, k-split for occupancy.
// 512 thr = 8 waves: wave (wq = w&3) owns q-rows [q0+wq*16,+16); kh = w>>2
// owns k-half [kh*1024, +1024).  Halves combined via LDS; kh=0 stores.
// Depth-1 register prefetch of B-frags (L2) and kw pair (LDS).
// ---------------------------------------------------------------------------
__global__ __launch_bounds__(512, 4) void k_main(const float* __restrict__ qw,
                                                 const float* __restrict__ kw,
                                                 const short8* __restrict__ vgs,
                                                 float* __restrict__ att,
                                                 float* __restrict__ rsum_o) {
    int hb  = blockIdx.y;
    int q0  = blockIdx.x * 64;
    int tid = threadIdx.x;
    int w   = tid >> 6;
    int wq  = w & 3;
    int kh  = w >> 2;
    int lane = tid & 63;
    int l15 = lane & 15, lg = lane >> 4;

    __shared__ float kws[2048];                 // 8 KB
    __shared__ float red[4][16][68];            // 17.4 KB half-combine buffer

    *(float4*)&kws[tid * 4] = *(const float4*)(kw + hb * 2048 + tid * 4);
    __syncthreads();

    float qwv = qw[hb * 2048 + q0 + wq * 16 + l15];
    const short8* bp = vgs + (size_t)hb * 16384 + lane;

    f32x4 acc0 = {0,0,0,0}, acc1 = {0,0,0,0}, acc2 = {0,0,0,0}, acc3 = {0,0,0,0};
    float sum = 0.f;

    int kb0 = kh * 32;
    const short8* pb = bp + (size_t)kb0 * 256;
    short8 cb0 = pb[0], cb1 = pb[64], cb2 = pb[128], cb3 = pb[192];
    float4 ckw0 = *(const float4*)&kws[kb0 * 32 + lg * 4];
    float4 ckw1 = *(const float4*)&kws[kb0 * 32 + lg * 4 + 16];

    for (int i = 0; i < 32; ++i) {
        short8 b0 = cb0, b1 = cb1, b2 = cb2, b3 = cb3;
        float4 kw0 = ckw0, kw1 = ckw1;
        if (i < 31) {                           // depth-1 prefetch
            const short8* nb = bp + (size_t)(kb0 + i + 1) * 256;
            cb0 = nb[0]; cb1 = nb[64]; cb2 = nb[128]; cb3 = nb[192];
            int nk = (kb0 + i + 1) * 32 + lg * 4;
            ckw0 = *(const float4*)&kws[nk];
            ckw1 = *(const float4*)&kws[nk + 16];
        }
        float e0 = fast_e(qwv + kw0.x), e1 = fast_e(qwv + kw0.y);
        float e2 = fast_e(qwv + kw0.z), e3 = fast_e(qwv + kw0.w);
        float e4 = fast_e(qwv + kw1.x), e5 = fast_e(qwv + kw1.y);
        float e6 = fast_e(qwv + kw1.z), e7 = fast_e(qwv + kw1.w);
        sum += ((e0 + e1) + (e2 + e3)) + ((e4 + e5) + (e6 + e7));
        union { unsigned int u[4]; short8 s; } af;
        af.u[0] = pk2(e0, e1);
        af.u[1] = pk2(e2, e3);
        af.u[2] = pk2(e4, e5);
        af.u[3] = pk2(e6, e7);
        acc0 = __builtin_amdgcn_mfma_f32_16x16x32_bf16(af.s, b0, acc0, 0, 0, 0);
        acc1 = __builtin_amdgcn_mfma_f32_16x16x32_bf16(af.s, b1, acc1, 0, 0, 0);
        acc2 = __builtin_amdgcn_mfma_f32_16x16x32_bf16(af.s, b2, acc2, 0, 0, 0);
        acc3 = __builtin_amdgcn_mfma_f32_16x16x32_bf16(af.s, b3, acc3, 0, 0, 0);
    }

    // intra-wave: sum over the 4 lg k-slices -> per-row half-sum (all lanes)
    sum += __shfl_xor(sum, 16);
    sum += __shfl_xor(sum, 32);

    // combine halves: kh=1 deposits, kh=0 accumulates + finishes
    if (kh == 1) {
        #define WR_(dt, accv) \
            red[wq][lg * 4 + 0][dt * 16 + l15] = accv[0]; \
            red[wq][lg * 4 + 1][dt * 16 + l15] = accv[1]; \
            red[wq][lg * 4 + 2][dt * 16 + l15] = accv[2]; \
            red[wq][lg * 4 + 3][dt * 16 + l15] = accv[3];
        WR_(0, acc0) WR_(1, acc1) WR_(2, acc2) WR_(3, acc3)
        #undef WR_
        if (lane < 16) red[wq][lane][64] = sum;
    }
    __syncthreads();
    if (kh == 0) {
        #define RD_(dt, accv) \
            accv[0] += red[wq][lg * 4 + 0][dt * 16 + l15]; \
            accv[1] += red[wq][lg * 4 + 1][dt * 16 + l15]; \
            accv[2] += red[wq][lg * 4 + 2][dt * 16 + l15]; \
            accv[3] += red[wq][lg * 4 + 3][dt * 16 + l15];
        RD_(0, acc0) RD_(1, acc1) RD_(2, acc2) RD_(3, acc3)
        #undef RD_
        float tot = sum + red[wq][l15][64];
        float rs = 1.0f / tot;
        if (lane < 16) rsum_o[hb * 2048 + q0 + wq * 16 + lane] = rs;

        int b_ = hb & 1, h = hb >> 1;
        float r0s = __shfl(rs, lg * 4 + 0);
        float r1s = __shfl(rs, lg * 4 + 1);
        float r2s = __shfl(rs, lg * 4 + 2);
        float r3s = __shfl(rs, lg * 4 + 3);
        float* ab = att + ((size_t)(b_ * 2048 + q0 + wq * 16 + lg * 4)) * 512 + h * 64 + l15;
        #define ST_(dt, accv) \
            ab[0 * 512 + dt * 16] = accv[0] * r0s; \
            ab[1 * 512 + dt * 16] = accv[1] * r1s; \
            ab[2 * 512 + dt * 16] = accv[2] * r2s; \
            ab[3 * 512 + dt * 16] = accv[3] * r3s;
        ST_(0, acc0) ST_(1, acc1) ST_(2, acc2) ST_(3, acc3)
        #undef ST_
    }
}

// ---------------------------------------------------------------------------
// K5: score writer — fully coalesced 256MB write (fp32 path, uses rsum).
// ---------------------------------------------------------------------------
__global__ void k_score(const float* __restrict__ qw, const float* __restrict__ kw,
                        const float* __restrict__ rsum, float* __restrict__ score) {
    int hb = blockIdx.y;
    int tid = threadIdx.x;
    __shared__ float kws[2048];
    *(float4*)&kws[tid * 8]     = *(const float4*)(kw + hb * 2048 + tid * 8);
    *(float4*)&kws[tid * 8 + 4] = *(const float4*)(kw + hb * 2048 + tid * 8 + 4);
    __syncthreads();
    int rl  = tid >> 5;
    int t32 = tid & 31;
    int q = blockIdx.x * 8 + rl;
    float qwv = qw[hb * 2048 + q];
    float rs  = rsum[hb * 2048 + q];
    float* out = score + ((size_t)(hb * 2048 + q)) * 2048;
    #pragma unroll
    for (int i = 0; i < 16; ++i) {
        int k = i * 128 + t32 * 4;
        float4 o;
        o.x = fast_e(qwv + kws[k + 0]) * rs;
        o.y = fast_e(qwv + kws[k + 1]) * rs;
        o.z = fast_e(qwv + kws[k + 2]) * rs;
        o.w = fast_e(qwv + kws[k + 3]) * rs;
        *(float4*)(out + k) = o;
    }
}

// ---------------------------------------------------------------------------
extern "C" void kernel_launch(void* const* d_in, const int* in_sizes, int n_in,
                              void* d_out, int out_size, void* d_ws, size_t ws_size,
                              hipStream_t stream) {
    (void)in_sizes; (void)n_in; (void)out_size; (void)ws_size;
    const float* q   = (const float*)d_in[0];
    const float* k   = (const float*)d_in[1];
    const float* v   = (const float*)d_in[2];
    const float* Wq  = (const float*)d_in[3];
    const float* bq  = (const float*)d_in[4];
    const float* Wk  = (const float*)d_in[5];
    const float* bk  = (const float*)d_in[6];
    const float* Wv  = (const float*)d_in[7];
    const float* bv  = (const float*)d_in[8];
    const float* wsc = (const float*)d_in[9];
    const float* Wd  = (const float*)d_in[10];
    const float* bd  = (const float*)d_in[11];

    float* out   = (float*)d_out;                       // (2,2048,512)
    float* score = out + (size_t)B_ * L_ * D_;          // (16,2048,2048)

    float* ws    = (float*)d_ws;
    float* wqwT  = ws;                 // 4096
    float* wkwT  = ws + 4096;          // 4096
    float* bqw   = ws + 8192;          // 8 (padded)
    float* bkw   = ws + 8256;          // 8 (padded)
    float* qw    = ws + 8704;          // 32768
    float* kw    = ws + 41472;         // 32768
    float* rsum  = ws + 74240;         // 32768
    float* vxg   = ws + 107008;        // 2,097,152 bf16 = 1,048,576 f32 slots
    float* att   = ws + 1155584;       // 2,097,152 f32
    float* WvF   = ws + 3252736;       // 262,144 bf16 = 131,072 f32 slots
    float* WdFh  = ws + 3383808;       // 131,072 f32 slots
    float* WdFl  = ws + 3514880;       // 131,072 f32 slots

    k_prep<<<dim3(4), dim3(256), 0, stream>>>(Wq, bq, Wk, bk, wsc, wqwT, wkwT, bqw, bkw);
    k_wconv<<<dim3(128, 2), dim3(256), 0, stream>>>(Wv, Wd,
        (unsigned short*)WvF, (unsigned short*)WdFh, (unsigned short*)WdFl);
    k_qwkw<<<dim3(2048), dim3(256), 0, stream>>>(q, k, wqwT, wkwT, bqw, bkw, qw, kw);
    k_mmA<<<dim3(64, 8), dim3(256), 0, stream>>>(v, (const short8*)WvF, bv,
        (unsigned short*)vxg);
    k_main<<<dim3(32, 16), dim3(512), 0, stream>>>(qw, kw, (const short8*)vxg, att, rsum);
    k_score<<<dim3(256, 16), dim3(256), 0, stream>>>(qw, kw, rsum, score);
    k_mmB<<<dim3(64, 8), dim3(256), 0, stream>>>(att, (const short8*)WdFh,
        (const short8*)WdFl, bd, out);
}